// Round 7
// baseline (806.415 us; speedup 1.0000x reference)
//
#include <hip/hip_runtime.h>
#include <math.h>
#include <string.h>

// ---------------- problem constants ----------------
constexpr int BB   = 2048;   // batch
constexpr int NW   = 151;    // windows
constexpr int NF   = 200;    // features
constexpr float BN_EPS = 1e-5f;

// All intermediate activations are stored WINDOW-MAJOR: H[(n*BB + b)*C + c].
// Layer/stats kernels (fixed n, 128 consecutive b) then stream fully
// contiguous 128*C blocks; fusedfinal reads 512B-aligned rows at 1MB stride.

typedef __bf16 bf16x8 __attribute__((ext_vector_type(8)));
typedef float  f32x4  __attribute__((ext_vector_type(4)));
typedef unsigned short u16x8 __attribute__((ext_vector_type(8)));

__device__ __forceinline__ unsigned short f2bf(float f) {
  unsigned int u; memcpy(&u, &f, 4);
  unsigned int r = (u + 0x7FFFu + ((u >> 16) & 1u)) >> 16;   // RNE
  return (unsigned short)r;
}
__device__ __forceinline__ float bf2f(unsigned short u) {
  unsigned int x = ((unsigned int)u) << 16;
  float f; memcpy(&f, &x, 4);
  return f;
}

// ---------------------------------------------------------------------------
// f layer 1 via sliding-window recurrence:
//   h[b,0,c]   = sum_i W[c,i] * x[b, i+50]
//   h[b,n+1,c] = h[b,n,c] + W[c,n] * (x[b,n] - x[b,n+50])
// ---------------------------------------------------------------------------
__global__ __launch_bounds__(256) void f1scan_k(
  const float* __restrict__ x, const float* __restrict__ W,
  float* __restrict__ Df)
{
  __shared__ float Wt[150*51];
  __shared__ float xs[800];
  __shared__ float lso[3200];
  const int t  = threadIdx.x;
  const int b0 = blockIdx.x * 4;
  const int ch = blockIdx.y;
  const int bl = t >> 6;
  const int c  = t & 63;

  for (int idx = t; idx < 50*150; idx += 256) {
    int cl = idx / 150, k = idx % 150;
    Wt[k*51 + cl] = W[(ch*50 + cl)*150 + k];
  }
  for (int idx = t; idx < 800; idx += 256) {
    int b2 = idx / 200, j = idx % 200;
    xs[idx] = x[(b0 + b2)*200 + j];
  }
  __syncthreads();

  float h = 0.f;
  if (c < 50) {
    #pragma unroll 5
    for (int i = 0; i < 150; i++)
      h += Wt[i*51 + c] * xs[bl*200 + 50 + i];
  }

  for (int n0 = 0; n0 < NW; n0 += 16) {
    const int cs = (NW - n0 < 16) ? (NW - n0) : 16;
    if (c < 50) {
      for (int l = 0; l < cs; l++) {
        int n = n0 + l;
        lso[bl*800 + l*50 + c] = h;
        if (n < 150) h += Wt[n*51 + c] * (xs[bl*200 + n] - xs[bl*200 + n + 50]);
      }
    }
    __syncthreads();
    const int tot = 4*cs*50;
    for (int idx = t; idx < tot; idx += 256) {
      int b2 = idx / (cs*50), rem = idx % (cs*50);
      int l = rem / 50, cc = rem % 50;
      Df[((size_t)(n0 + l)*BB + (b0 + b2))*100 + ch*50 + cc] = lso[b2*800 + l*50 + cc];
    }
    __syncthreads();
  }
}

// ---------------------------------------------------------------------------
// Per-window BN stats (sum, sumsq) over (b, c).  Window-major input.
// ---------------------------------------------------------------------------
template<int C>
__global__ __launch_bounds__(256) void bnstats_k(
  const float* __restrict__ H, float* __restrict__ stats)
{
  __shared__ float red[8];
  const int n = blockIdx.x, b0 = blockIdx.y * 256, t = threadIdx.x;
  const float* base = H + (size_t)n*BB*C + (size_t)b0*C;
  float s1 = 0.f, s2 = 0.f;
  for (int idx = t; idx < 256*C; idx += 256) {
    float v = base[idx];
    s1 += v; s2 += v*v;
  }
  #pragma unroll
  for (int off = 32; off; off >>= 1) {
    s1 += __shfl_down(s1, off); s2 += __shfl_down(s2, off);
  }
  if ((t & 63) == 0) { red[(t>>6)*2] = s1; red[(t>>6)*2+1] = s2; }
  __syncthreads();
  if (t == 0) {
    atomicAdd(&stats[2*n],   red[0]+red[2]+red[4]+red[6]);
    atomicAdd(&stats[2*n+1], red[1]+red[3]+red[5]+red[7]);
  }
}

// ---------------------------------------------------------------------------
// Weight pre-conversion: fp32 W[OUT][IN] -> padded split-bf16 Wb.
// ---------------------------------------------------------------------------
__global__ __launch_bounds__(256) void wcvt_k(
  const float* __restrict__ W, unsigned short* __restrict__ Wb,
  int OUT, int IN, int KP, int total)
{
  int idx = blockIdx.x*256 + threadIdx.x;
  if (idx >= total) return;
  int o = idx / KP, k = idx % KP;
  float v = (o < OUT && k < IN) ? W[o*IN + k] : 0.f;
  unsigned short hi = f2bf(v);
  float lo = v - bf2f(hi);
  Wb[idx] = hi;
  Wb[total + idx] = f2bf(lo);
}

// ---------------------------------------------------------------------------
// MFMA layer: per (window n, 128-batch chunk):  H = act(bn(X)) @ W^T
// LDS-free; split-bf16 (hi/lo) x3 MFMAs for ~fp32 accuracy.
// MODE 0: raw sliding window of x (b-major input, layout fixed).
// MODE 2: window-major activation input.
// ---------------------------------------------------------------------------
template<int IN, int OUT, int MODE, int ACT>
__global__ __launch_bounds__(256) void layer_mfma_k(
    const float* __restrict__ X, const unsigned short* __restrict__ Wb,
    const float* __restrict__ statsPrev, float* __restrict__ H,
    float* __restrict__ statsOut)
{
  constexpr int KP   = (IN + 31) & ~31;    // K padded to 32
  constexpr int OUTP = (OUT + 15) & ~15;   // N padded to 16
  constexpr int KC   = KP / 32;
  constexpr int NT   = OUTP / 16;
  constexpr int MT   = 2;                  // m-tiles per wave

  __shared__ float red[8];
  const int n    = blockIdx.x;
  const int b0   = blockIdx.y * 128;
  const int t    = threadIdx.x;
  const int w    = t >> 6;
  const int lane = t & 63;
  const int l16  = lane & 15;
  const int quad = lane >> 4;

  float mean = 0.f, rstd = 1.f;
  if constexpr (MODE == 2) {
    const float cnt = (float)BB * (float)IN;
    mean = statsPrev[2*n] / cnt;
    float var = statsPrev[2*n+1] / cnt - mean*mean;
    rstd = rsqrtf(var + BN_EPS);
  }

  bf16x8 af_hi[MT][KC], af_lo[MT][KC];
  #pragma unroll
  for (int mt = 0; mt < MT; mt++) {
    const int bb = b0 + (w*MT + mt)*16 + l16;
    const float* xr = (MODE == 0)
        ? (X + (size_t)bb*NF + n)
        : (X + ((size_t)n*BB + bb)*IN);
    #pragma unroll
    for (int kc = 0; kc < KC; kc++) {
      const int k0 = kc*32 + quad*8;
      float vv[8];
      if constexpr (MODE == 0) {
        #pragma unroll
        for (int j = 0; j < 8; j++) {
          int k = k0 + j;
          vv[j] = (k < IN) ? xr[k] : 0.f;
        }
      } else if constexpr (IN % 4 == 0) {
        #pragma unroll
        for (int g = 0; g < 2; g++) {
          int kg = k0 + 4*g;
          if (kg < IN) {
            float4 f = *(const float4*)(xr + kg);
            vv[4*g] = f.x; vv[4*g+1] = f.y; vv[4*g+2] = f.z; vv[4*g+3] = f.w;
          } else {
            vv[4*g] = 0.f; vv[4*g+1] = 0.f; vv[4*g+2] = 0.f; vv[4*g+3] = 0.f;
          }
        }
      } else if constexpr (IN % 2 == 0) {
        #pragma unroll
        for (int g = 0; g < 4; g++) {
          int kg = k0 + 2*g;
          if (kg < IN) {
            float2 f = *(const float2*)(xr + kg);
            vv[2*g] = f.x; vv[2*g+1] = f.y;
          } else {
            vv[2*g] = 0.f; vv[2*g+1] = 0.f;
          }
        }
      } else {
        #pragma unroll
        for (int j = 0; j < 8; j++) {
          int k = k0 + j;
          vv[j] = (k < IN) ? xr[k] : 0.f;
        }
      }
      u16x8 hi, lo;
      #pragma unroll
      for (int j = 0; j < 8; j++) {
        bool valid = (k0 + j) < IN;
        float v;
        if constexpr (MODE == 0) {
          v = vv[j];
        } else {
          float z = (vv[j] - mean) * rstd;
          float a = (ACT == 1) ? ((z >= 0.f) ? z : 0.01f*z) : tanhf(z);
          v = valid ? a : 0.f;
        }
        unsigned short h16 = f2bf(v);
        hi[j] = h16;
        lo[j] = f2bf(v - bf2f(h16));
      }
      af_hi[mt][kc] = __builtin_bit_cast(bf16x8, hi);
      af_lo[mt][kc] = __builtin_bit_cast(bf16x8, lo);
    }
  }

  float s1 = 0.f, s2 = 0.f;
  #pragma unroll
  for (int nt = 0; nt < NT; nt++) {
    const int c = nt*16 + l16;
    f32x4 acc[MT];
    #pragma unroll
    for (int mt = 0; mt < MT; mt++) acc[mt] = (f32x4){0.f, 0.f, 0.f, 0.f};
    #pragma unroll
    for (int kc = 0; kc < KC; kc++) {
      const unsigned short* wp = Wb + (size_t)(nt*16 + l16)*KP + kc*32 + quad*8;
      bf16x8 wh = *(const bf16x8*)wp;
      bf16x8 wl = *(const bf16x8*)(wp + OUTP*KP);
      #pragma unroll
      for (int mt = 0; mt < MT; mt++) {
        acc[mt] = __builtin_amdgcn_mfma_f32_16x16x32_bf16(af_hi[mt][kc], wh, acc[mt], 0, 0, 0);
        acc[mt] = __builtin_amdgcn_mfma_f32_16x16x32_bf16(af_lo[mt][kc], wh, acc[mt], 0, 0, 0);
        acc[mt] = __builtin_amdgcn_mfma_f32_16x16x32_bf16(af_hi[mt][kc], wl, acc[mt], 0, 0, 0);
      }
    }
    #pragma unroll
    for (int mt = 0; mt < MT; mt++) {
      const int mrow = (w*MT + mt)*16 + quad*4;
      #pragma unroll
      for (int r = 0; r < 4; r++) {
        float v = acc[mt][r];
        s1 += v; s2 += v*v;
        if (c < OUT)
          H[((size_t)n*BB + (b0 + mrow + r))*OUT + c] = v;
      }
    }
  }

  #pragma unroll
  for (int off = 32; off; off >>= 1) {
    s1 += __shfl_down(s1, off); s2 += __shfl_down(s2, off);
  }
  if (lane == 0) { red[w*2] = s1; red[w*2+1] = s2; }
  __syncthreads();
  if (t == 0) {
    atomicAdd(&statsOut[2*n],   red[0]+red[2]+red[4]+red[6]);
    atomicAdd(&statsOut[2*n+1], red[1]+red[3]+red[5]+red[7]);
  }
}

// ---------------------------------------------------------------------------
// Precompute BN (mean, rstd) tables for the two layer-3 stat vectors.
// ---------------------------------------------------------------------------
__global__ void mr_k(const float* __restrict__ sP, const float* __restrict__ sQ,
                     float* __restrict__ mrP, float* __restrict__ mrQ)
{
  int n = threadIdx.x;
  if (n >= NW) return;
  const float cnt = (float)BB * 128.f;
  float m = sP[2*n] / cnt;
  float var = sP[2*n+1] / cnt - m*m;
  mrP[2*n] = m; mrP[2*n+1] = rsqrtf(var + BN_EPS);
  m = sQ[2*n] / cnt;
  var = sQ[2*n+1] / cnt - m*m;
  mrQ[2*n] = m; mrQ[2*n+1] = rsqrtf(var + BN_EPS);
}

// ---------------------------------------------------------------------------
// Per-(b,d): 1/max(||leaky(bn(h3))||_n, 1e-12)   (window-major input)
// ---------------------------------------------------------------------------
__global__ __launch_bounds__(256) void normstats_k(
  const float* __restrict__ H, const float* __restrict__ mr,
  float* __restrict__ rinv)
{
  int idx = blockIdx.x*256 + threadIdx.x;   // over B*128
  int b = idx >> 7, d = idx & 127;
  float s = 0.f;
  #pragma unroll 4
  for (int n = 0; n < NW; n++) {
    float m = mr[2*n];
    float r = mr[2*n+1];
    float v = H[((size_t)n*BB + b)*128 + d];
    float z = (v - m) * r;
    float lv = (z >= 0.f) ? z : 0.01f*z;
    s += lv*lv;
  }
  rinv[idx] = 1.f / fmaxf(sqrtf(s), 1e-12f);
}

__global__ void invperm_k(const int* __restrict__ perm, int* __restrict__ inv) {
  int j = threadIdx.x;
  if (j < NW) inv[perm[j]] = j;
}

// ---------------------------------------------------------------------------
// Fused normalize + final einsum. One block per batch element b.
//  - Q tile in LDS in MFMA-fragment order (conflict-free ds ops).
//  - A-fragments built per-strip straight from global fp32.
//  - Output strips staged in per-wave LDS then written as contiguous rows.
// Window-major activation input: row (n,b) at (n*BB+b)*128 (512B aligned).
// ---------------------------------------------------------------------------
__global__ __launch_bounds__(256) void fusedfinal_k(
  const float* __restrict__ P32, const float* __restrict__ Q32,
  const float* __restrict__ mrP, const float* __restrict__ mrQ,
  const float* __restrict__ rinvP, const float* __restrict__ rinvQ,
  const int* __restrict__ inv, float* __restrict__ out)
{
  __shared__ unsigned short Qf[40*64*8];   // 40960 B, fragment-ordered
  __shared__ float stgbuf[4][16*154];      // 39424 B per-wave strip staging
  __shared__ int invs[NW];

  const int b    = blockIdx.x;
  const int t    = threadIdx.x;
  const int w    = t >> 6;
  const int lane = t & 63;
  const int l16  = lane & 15;
  const int quad = lane >> 4;

  for (int i = t; i < NW; i += 256) invs[i] = inv[i];

  // ---- phase 1: fill Q bf16 fragments (BN + leaky + rinv + f2bf) ----
  {
    const int kcw = w;                       // wave w owns kc column w
    const int c0  = kcw*32 + quad*8;
    float ri[8];
    {
      float4 r0 = *(const float4*)&rinvQ[(b<<7) + c0];
      float4 r1 = *(const float4*)&rinvQ[(b<<7) + c0 + 4];
      ri[0]=r0.x; ri[1]=r0.y; ri[2]=r0.z; ri[3]=r0.w;
      ri[4]=r1.x; ri[5]=r1.y; ri[6]=r1.z; ri[7]=r1.w;
    }
    #pragma unroll
    for (int tj = 0; tj < 10; tj++) {
      const int n = tj*16 + l16;
      u16x8 hh;
      if (n < NW) {
        const float mQ = mrQ[2*n];
        const float rQ = mrQ[2*n+1];
        const float* qrow = Q32 + ((size_t)n*BB + b)*128 + c0;
        float4 u0 = *(const float4*)qrow;
        float4 u1 = *(const float4*)(qrow + 4);
        float e[8] = {u0.x, u0.y, u0.z, u0.w, u1.x, u1.y, u1.z, u1.w};
        #pragma unroll
        for (int j = 0; j < 8; j++) {
          float z = (e[j] - mQ) * rQ;
          z = ((z >= 0.f) ? z : 0.01f*z) * ri[j];
          hh[j] = f2bf(z);
        }
      } else {
        #pragma unroll
        for (int j = 0; j < 8; j++) hh[j] = 0;
      }
      *(bf16x8*)(Qf + ((size_t)(tj*4 + kcw)*64 + lane)*8) =
          __builtin_bit_cast(bf16x8, hh);
    }
  }
  __syncthreads();

  // per-lane rinvP slice for A-fragment columns (fixed by quad)
  float riA[4][8];
  #pragma unroll
  for (int kc = 0; kc < 4; kc++) {
    const int c0 = kc*32 + quad*8;
    float4 r0 = *(const float4*)&rinvP[(b<<7) + c0];
    float4 r1 = *(const float4*)&rinvP[(b<<7) + c0 + 4];
    riA[kc][0]=r0.x; riA[kc][1]=r0.y; riA[kc][2]=r0.z; riA[kc][3]=r0.w;
    riA[kc][4]=r1.x; riA[kc][5]=r1.y; riA[kc][6]=r1.z; riA[kc][7]=r1.w;
  }

  // ---- phase 2+3: MFMA strips + staged contiguous row writes ----
  float* ob = out + (size_t)b*152*NW;
  float* stg = stgbuf[w];
  const float NEG_BIG = -3.0e38f;

  for (int ti = w; ti < 10; ti += 4) {
    const int mbase = ti*16;
    // A-fragment: global fp32 row -> BN + leaky + rinv -> bf16 (in regs)
    const int arow = (mbase + l16 < NW) ? (mbase + l16) : (NW-1);
    const float mP = mrP[2*arow];
    const float rP = mrP[2*arow+1];
    const float* prow = P32 + ((size_t)arow*BB + b)*128;
    bf16x8 af[4];
    #pragma unroll
    for (int kc = 0; kc < 4; kc++) {
      const int c0 = kc*32 + quad*8;
      float4 v0 = *(const float4*)(prow + c0);
      float4 v1 = *(const float4*)(prow + c0 + 4);
      float e[8] = {v0.x, v0.y, v0.z, v0.w, v1.x, v1.y, v1.z, v1.w};
      u16x8 hh;
      #pragma unroll
      for (int j = 0; j < 8; j++) {
        float z = (e[j] - mP) * rP;
        z = ((z >= 0.f) ? z : 0.01f*z) * riA[kc][j];
        hh[j] = f2bf(z);
      }
      af[kc] = __builtin_bit_cast(bf16x8, hh);
    }

    #pragma unroll 2
    for (int tj = 0; tj < 10; tj++) {
      f32x4 acc = {0.f, 0.f, 0.f, 0.f};
      #pragma unroll
      for (int kc = 0; kc < 4; kc++) {
        bf16x8 bf = *(const bf16x8*)(Qf + ((size_t)(tj*4 + kc)*64 + lane)*8);
        acc = __builtin_amdgcn_mfma_f32_16x16x32_bf16(af[kc], bf, acc, 0, 0, 0);
      }
      const int col = tj*16 + l16;
      if (col < NW) {
        #pragma unroll
        for (int r = 0; r < 4; r++)
          stg[(quad*4 + r)*154 + col] = acc[r];
      }
    }
    // per-wave write of the 16-row strip; rows are contiguous 604B streams
    for (int r = 0; r < 16; r++) {
      const int mm = mbase + r;
      if (mm >= NW) break;
      const int orow = 1 + invs[mm];
      float* dst = ob + (size_t)orow*NW;
      for (int col = lane; col < NW; col += 64) {
        float v = stg[r*154 + col] * 100.f;
        if (col == mm) { ob[mm] = v; v = NEG_BIG; }
        dst[col] = v;
      }
    }
  }
}

// ---------------------------------------------------------------------------
extern "C" void kernel_launch(void* const* d_in, const int* in_sizes, int n_in,
                              void* d_out, int out_size, void* d_ws, size_t ws_size,
                              hipStream_t stream) {
  const float* x   = (const float*)d_in[0];
  const float* gW0 = (const float*)d_in[1];
  const float* gW1 = (const float*)d_in[2];
  const float* gW2 = (const float*)d_in[3];
  const float* fW0 = (const float*)d_in[4];
  const float* fW1 = (const float*)d_in[5];
  const float* fW2 = (const float*)d_in[6];
  const int*  perm = (const int*)d_in[7];
  float* out = (float*)d_out;
  char* ws = (char*)d_ws;

  float* stats = (float*)ws;                       // 6 x 302 floats
  int*   inv   = (int*)(ws + 8192);                // 604 B
  float* mrP   = (float*)(ws + 10240);             // 302 floats
  float* mrQ   = (float*)(ws + 11648);             // 302 floats
  float* rinvP = (float*)(ws + 16384);             // 2048*128 (used late)
  float* rinvQ = rinvP + 2048*128;
  float* Ag = (float*)(ws + 16384 + 2*1048576);    // h1g: 151*2048*50
  float* Bg = Ag + 15462400;                       // h2g: 151*2048*25
  float* Cg = Bg + 7731200;                        // h3g (raw)
  float* Df = Cg + 39583744;                       // h1f: 151*2048*100
  float* Ff = Df + 30924800;                       // h3f (raw)
  float* Ef = Ag;                                  // h2f reuses dead h1g

  // split-bf16 weights live in the rinvP area (dead until normstats_k):
  unsigned short* Wbase = (unsigned short*)(ws + 16384);
  unsigned short* Wg1 = Wbase;            // 64x64   -> 2*4096
  unsigned short* Wg2 = Wbase + 8192;     // 32x64   -> 2*2048
  unsigned short* Wg3 = Wbase + 12288;    // 128x32  -> 2*4096
  unsigned short* Wf2 = Wbase + 20480;    // 64x128  -> 2*8192
  unsigned short* Wf3 = Wbase + 36864;    // 128x64  -> 2*8192  (ends 53248)

  float* sg1 = stats,        *sg2 = stats + 302,  *sg3 = stats + 604;
  float* sf1 = stats + 906,  *sf2 = stats + 1208, *sf3 = stats + 1510;

  hipMemsetAsync(stats, 0, 1812*sizeof(float), stream);
  invperm_k<<<1, 192, 0, stream>>>(perm, inv);

  // weight pre-conversion (tiny)
  wcvt_k<<<16, 256, 0, stream>>>(gW0, Wg1,  50,  50,  64, 4096);
  wcvt_k<<< 8, 256, 0, stream>>>(gW1, Wg2,  25,  50,  64, 2048);
  wcvt_k<<<16, 256, 0, stream>>>(gW2, Wg3, 128,  25,  32, 4096);
  wcvt_k<<<32, 256, 0, stream>>>(fW1, Wf2,  50, 100, 128, 8192);
  wcvt_k<<<32, 256, 0, stream>>>(fW2, Wf3, 128,  50,  64, 8192);

  // f layer 1 via sliding-window scan + separate stats pass
  f1scan_k<<<dim3(BB/4, 2), 256, 0, stream>>>(x, fW0, Df);
  bnstats_k<100><<<dim3(NW, 8), 256, 0, stream>>>(Df, sf1);

  dim3 gl2(NW, BB/128);
  layer_mfma_k< 50,  50, 0, 0><<<gl2, 256, 0, stream>>>(x,  Wg1, nullptr, Ag, sg1);
  layer_mfma_k< 50,  25, 2, 1><<<gl2, 256, 0, stream>>>(Ag, Wg2, sg1,     Bg, sg2);
  layer_mfma_k< 25, 128, 2, 1><<<gl2, 256, 0, stream>>>(Bg, Wg3, sg2,     Cg, sg3);
  layer_mfma_k<100,  50, 2, 2><<<gl2, 256, 0, stream>>>(Df, Wf2, sf1,     Ef, sf2);
  layer_mfma_k< 50, 128, 2, 1><<<gl2, 256, 0, stream>>>(Ef, Wf3, sf2,     Ff, sf3);

  // (mean, rstd) tables for the layer-3 BN (used by all downstream kernels)
  mr_k<<<1, 192, 0, stream>>>(sg3, sf3, mrP, mrQ);

  // per-(b,d) inverse norms
  normstats_k<<<1024, 256, 0, stream>>>(Cg, mrP, rinvP);
  normstats_k<<<1024, 256, 0, stream>>>(Ff, mrQ, rinvQ);

  // fused normalize + einsum + masked scatter
  fusedfinal_k<<<BB, 256, 0, stream>>>(Cg, Ff, mrP, mrQ, rinvP, rinvQ, inv, out);
  (void)in_sizes; (void)n_in; (void)out_size; (void)ws_size;
}